// Round 2
// baseline (985.100 us; speedup 1.0000x reference)
//
#include <hip/hip_runtime.h>

// Problem dims (fixed by reference)
#define DH 128
#define DW 128
#define DB 8
#define DC 64
constexpr int HW = DH * DW;

// ---------------- conv 3x3 SAME, stride 1, direct, fp32 ----------------
// Block: 256 threads = 16x16 spatial tile. Each thread computes COUT_BLK
// output channels for its pixel. Input channel tile (18x18 incl halo)
// staged in LDS once per ci; weights are block-uniform -> scalar loads.
template<int CIN, int COUT, int COUT_BLK, bool HAS_BIAS>
__global__ __launch_bounds__(256) void conv3x3_kernel(
    const float* __restrict__ x, const float* __restrict__ w,
    const float* __restrict__ bias, float* __restrict__ out)
{
    __shared__ float smem[18 * 18];
    const int tid = threadIdx.x;
    const int tx = tid & 15;
    const int ty = tid >> 4;
    const int tiles_w = DW / 16;
    const int tile_y = (blockIdx.x / tiles_w) * 16;
    const int tile_x = (blockIdx.x % tiles_w) * 16;
    const int co0 = blockIdx.y * COUT_BLK;
    const int b = blockIdx.z;

    float acc[COUT_BLK];
#pragma unroll
    for (int i = 0; i < COUT_BLK; ++i) acc[i] = 0.f;

    const float* xb = x + (size_t)b * CIN * HW;

    for (int ci = 0; ci < CIN; ++ci) {
        __syncthreads();
        // stage 18x18 halo tile for this input channel
        for (int i = tid; i < 18 * 18; i += 256) {
            int r = i / 18, cc = i - r * 18;
            int iy = tile_y + r - 1, ix = tile_x + cc - 1;
            float v = 0.f;
            if (iy >= 0 && iy < DH && ix >= 0 && ix < DW)
                v = xb[(size_t)ci * HW + iy * DW + ix];
            smem[i] = v;
        }
        __syncthreads();
        float v[9];
#pragma unroll
        for (int dy = 0; dy < 3; ++dy)
#pragma unroll
            for (int dx = 0; dx < 3; ++dx)
                v[dy * 3 + dx] = smem[(ty + dy) * 18 + (tx + dx)];
#pragma unroll
        for (int co = 0; co < COUT_BLK; ++co) {
            const float* wp = w + ((size_t)(co0 + co) * CIN + ci) * 9;
#pragma unroll
            for (int t = 0; t < 9; ++t)
                acc[co] = fmaf(v[t], wp[t], acc[co]);
        }
    }

    const int oy = tile_y + ty, ox = tile_x + tx;
#pragma unroll
    for (int co = 0; co < COUT_BLK; ++co) {
        float r = acc[co];
        if (HAS_BIAS) r += bias[co0 + co];
        out[((size_t)b * COUT + co0 + co) * HW + oy * DW + ox] = r;
    }
}

// ---------------- deformable bilinear gather ----------------
// offsets_ has shape (B, 2C, H, W); the torch-contiguous reshape
// (b*c, h*w, 2) means offset pair for (b, ci, p) is the float2 at
// linear float2-index (b*C + ci)*HW + p.
__global__ __launch_bounds__(256) void deform_kernel(
    const float* __restrict__ x, const float* __restrict__ off,
    float* __restrict__ xdef)
{
    int idx = blockIdx.x * 256 + threadIdx.x;  // over B*C*H*W
    const int total = DB * DC * HW;
    if (idx >= total) return;
    int p = idx & (HW - 1);
    int bc = idx >> 14;  // /HW (HW = 16384)

    float2 o = reinterpret_cast<const float2*>(off)[(size_t)bc * HW + p];
    int gy = p >> 7;        // /W
    int gx = p & (DW - 1);  // %W

    float cy = fminf(fmaxf(o.x + (float)gy, 0.f), (float)(DH - 1));
    float cx = fminf(fmaxf(o.y + (float)gx, 0.f), (float)(DW - 1));

    float y0f = floorf(cy), x0f = floorf(cx);
    int y0 = (int)y0f, x0 = (int)x0f;
    int y1 = (int)ceilf(cy), x1 = (int)ceilf(cx);

    const float* plane = x + (size_t)bc * HW;
    float v_lt = plane[y0 * DW + x0];
    float v_rb = plane[y1 * DW + x1];
    float v_lb = plane[y0 * DW + x1];
    float v_rt = plane[y1 * DW + x0];

    float dy = cy - y0f, dx = cx - x0f;
    float v_t = fmaf(dy, v_rt - v_lt, v_lt);
    float v_b = fmaf(dy, v_rb - v_lb, v_lb);
    xdef[idx] = fmaf(dx, v_b - v_t, v_t);
}

extern "C" void kernel_launch(void* const* d_in, const int* in_sizes, int n_in,
                              void* d_out, int out_size, void* d_ws, size_t ws_size,
                              hipStream_t stream) {
    const float* x      = (const float*)d_in[0];  // (8,64,128,128)
    const float* W_off  = (const float*)d_in[1];  // (128,64,3,3)
    const float* W_conv = (const float*)d_in[2];  // (64,64,3,3)
    const float* b_conv = (const float*)d_in[3];  // (64,)

    float* offs = (float*)d_ws;                       // B*2C*HW floats (67 MB)
    float* xdef = offs + (size_t)DB * 2 * DC * HW;    // B*C*HW floats (33.5 MB)
    float* out  = (float*)d_out;

    // 1) offset conv: (8,64,...) -> (8,128,...)
    {
        dim3 grid((DH / 16) * (DW / 16), (2 * DC) / 16, DB);
        conv3x3_kernel<DC, 2 * DC, 16, false><<<grid, 256, 0, stream>>>(
            x, W_off, nullptr, offs);
    }
    // 2) deformable gather
    {
        int total = DB * DC * HW;
        deform_kernel<<<total / 256, 256, 0, stream>>>(x, offs, xdef);
    }
    // 3) following conv + bias: (8,64,...) -> (8,64,...)
    {
        dim3 grid((DH / 16) * (DW / 16), DC / 16, DB);
        conv3x3_kernel<DC, DC, 16, true><<<grid, 256, 0, stream>>>(
            xdef, W_conv, b_conv, out);
    }
}

// Round 4
// 194.665 us; speedup vs baseline: 5.0605x; 5.0605x over previous
//
#include <hip/hip_runtime.h>

#define DH 128
#define DW 128
#define DB 8
#define DC 64
constexpr int HW = DH * DW;

typedef __attribute__((ext_vector_type(4))) float f32x4;
typedef __attribute__((ext_vector_type(8))) short bf16x8;
typedef __attribute__((ext_vector_type(4))) unsigned int u32x4;

__device__ __forceinline__ unsigned short f2b(float f) {
    unsigned int u = __builtin_bit_cast(unsigned int, f);
    u = (u + 0x7FFFu + ((u >> 16) & 1u)) >> 16;   // RNE
    return (unsigned short)u;
}
__device__ __forceinline__ float b2f(unsigned short h) {
    unsigned int u = ((unsigned int)h) << 16;
    return __builtin_bit_cast(float, u);
}

// ---------- NCHW fp32 -> HWC bf16 transpose: xh[b][p][ci] ----------
__global__ __launch_bounds__(256) void xpose_kernel(
    const float* __restrict__ x, unsigned short* __restrict__ xh)
{
    __shared__ unsigned short sm[64 * 80];   // [pix][ci], pad 80 (byte stride 160)
    const int b = blockIdx.y;
    const int p0 = blockIdx.x * 64;
    const int t = threadIdx.x;
    const int ci = t >> 2, q = t & 3;
    const float* xr = x + ((size_t)b * 64 + ci) * HW + p0;
#pragma unroll
    for (int j = 0; j < 4; ++j) {
        int pix = (j * 4 + q) * 4;           // lanes q=0..3 -> 64B contiguous
        float4 v = *(const float4*)(xr + pix);
        sm[(pix + 0) * 80 + ci] = f2b(v.x);
        sm[(pix + 1) * 80 + ci] = f2b(v.y);
        sm[(pix + 2) * 80 + ci] = f2b(v.z);
        sm[(pix + 3) * 80 + ci] = f2b(v.w);
    }
    __syncthreads();
    unsigned short* outp = xh + ((size_t)b * HW + p0) * 64;
    for (int i = t; i < 512; i += 256) {
        int pix = i >> 3, cq = i & 7;
        u32x4 v = *(const u32x4*)(sm + pix * 80 + cq * 8);
        *(u32x4*)(outp + pix * 64 + cq * 8) = v;
    }
}

// ---------- weights OIHW fp32 -> [tap][co][ci] bf16 ----------
__global__ __launch_bounds__(256) void wprep_kernel(
    const float* __restrict__ w, unsigned short* __restrict__ wt, int cout)
{
    int id = blockIdx.x * 256 + threadIdx.x;
    int total = cout * 64 * 9;
    if (id >= total) return;
    int t = id / (cout * 64);
    int rem = id - t * cout * 64;
    int co = rem >> 6, ci = rem & 63;
    wt[id] = f2b(w[((co * 64) + ci) * 9 + t]);
}

// ---------- conv 3x3 as implicit GEMM, bf16 MFMA ----------
// Block: 256 thr (4 waves). Tile: 8x8 pixels x COUT. Halo 10x10x64 bf16 in
// LDS (XOR-swizzled). K-loop: 9 taps x 2 ci-chunks -> 18 MFMA k-steps.
template<int COUT, int M_PER_WAVE, bool HWC_BF16_OUT>
__global__ __launch_bounds__(256) void conv_mfma_kernel(
    const unsigned short* __restrict__ xh,   // bf16 HWC [b][p][64]
    const unsigned short* __restrict__ wt,   // bf16 [9][COUT][64]
    const float* __restrict__ bias,
    void* __restrict__ outp)
{
    __shared__ char sm[12800];
    const int tid = threadIdx.x;
    const int b = blockIdx.y;
    const int tile = blockIdx.x;
    const int ty0 = (tile >> 4) * 8, tx0 = (tile & 15) * 8;
    const unsigned short* xb = xh + (size_t)b * HW * 64;

    // stage 10x10 halo x 64ci, 16B tasks, swizzle byte ^= (hp&7)<<4
    for (int i = tid; i < 800; i += 256) {
        int hp = i >> 3, cq = i & 7;
        int hy = hp / 10, hx = hp - hy * 10;
        int gy = ty0 + hy - 1, gx = tx0 + hx - 1;
        u32x4 v = {0u, 0u, 0u, 0u};
        if ((unsigned)gy < 128u && (unsigned)gx < 128u)
            v = *(const u32x4*)(xb + (size_t)((gy << 7) + gx) * 64 + cq * 8);
        int byte = (hp * 128 + cq * 16) ^ ((hp & 7) << 4);
        *(u32x4*)(sm + byte) = v;
    }
    __syncthreads();

    const int lane = tid & 63;
    const int wv = tid >> 6;
    const int n = lane & 15;
    const int kg = lane >> 4;                 // 0..3
    const int cobase = wv * (M_PER_WAVE * 16);

    int base_hp[4];
#pragma unroll
    for (int nt = 0; nt < 4; ++nt) {
        int tp = nt * 16 + n;
        base_hp[nt] = (tp >> 3) * 10 + (tp & 7);
    }

    f32x4 acc[M_PER_WAVE][4];
#pragma unroll
    for (int mi = 0; mi < M_PER_WAVE; ++mi)
#pragma unroll
        for (int ni = 0; ni < 4; ++ni) acc[mi][ni] = (f32x4){0.f, 0.f, 0.f, 0.f};

#pragma unroll
    for (int ty = 0; ty < 3; ++ty)
#pragma unroll
    for (int tx = 0; tx < 3; ++tx) {
        const int t9 = ty * 3 + tx;
        const int toff = ty * 10 + tx;
#pragma unroll
        for (int kk = 0; kk < 2; ++kk) {
            const int ci0 = kk * 32 + kg * 8;
            bf16x8 a[M_PER_WAVE];
#pragma unroll
            for (int mi = 0; mi < M_PER_WAVE; ++mi)
                a[mi] = *(const bf16x8*)(wt + (size_t)(t9 * COUT + cobase + mi * 16 + n) * 64 + ci0);
#pragma unroll
            for (int ni = 0; ni < 4; ++ni) {
                int hp = base_hp[ni] + toff;
                int byte = (hp * 128 + ci0 * 2) ^ ((hp & 7) << 4);
                bf16x8 bv = *(const bf16x8*)(sm + byte);
#pragma unroll
                for (int mi = 0; mi < M_PER_WAVE; ++mi)
                    acc[mi][ni] = __builtin_amdgcn_mfma_f32_16x16x32_bf16(
                        a[mi], bv, acc[mi][ni], 0, 0, 0);
            }
        }
    }

    // epilogue: D layout col=lane&15 (pixel), row=(lane>>4)*4+reg (co)
#pragma unroll
    for (int ni = 0; ni < 4; ++ni) {
        int tp = ni * 16 + n;
        int gp = (ty0 + (tp >> 3)) * 128 + tx0 + (tp & 7);
        if (HWC_BF16_OUT) {
            unsigned short* o = (unsigned short*)outp + ((size_t)b * HW + gp) * COUT;
#pragma unroll
            for (int mi = 0; mi < M_PER_WAVE; ++mi) {
                int co = cobase + mi * 16 + kg * 4;
                uint2 pk;
                pk.x = (unsigned)f2b(acc[mi][ni][0]) | ((unsigned)f2b(acc[mi][ni][1]) << 16);
                pk.y = (unsigned)f2b(acc[mi][ni][2]) | ((unsigned)f2b(acc[mi][ni][3]) << 16);
                *(uint2*)(o + co) = pk;
            }
        } else {
            float* o = (float*)outp + (size_t)b * COUT * HW + gp;
#pragma unroll
            for (int mi = 0; mi < M_PER_WAVE; ++mi) {
                int co = cobase + mi * 16 + kg * 4;
#pragma unroll
                for (int r = 0; r < 4; ++r)
                    o[(size_t)(co + r) * HW] = acc[mi][ni][r] + bias[co + r];
            }
        }
    }
}

// ---------- deformable bilinear gather (HWC in/out) ----------
// Torch-view semantics (flat-order identical to passing baseline):
// y-offset for (b,ci,p) = conv1 channel ch=2ci+(p>>13) at pixel pp=(2p)&16383,
// x-offset = same channel at pixel pp+1.
__global__ __launch_bounds__(256) void deform_kernel(
    const unsigned short* __restrict__ xh,     // bf16 HWC [b][p][64]
    const unsigned short* __restrict__ offs,   // bf16 HWC [b][p][128]
    unsigned short* __restrict__ xdef)         // bf16 HWC [b][p][64]
{
    int idx = blockIdx.x * 256 + threadIdx.x;  // (b, p, ci), ci fastest
    int ci = idx & 63;
    int bp = idx >> 6;
    int p = bp & (HW - 1);
    int b = bp >> 14;
    int ch = 2 * ci + (p >> 13);
    int pp = (2 * p) & (HW - 1);
    const unsigned short* ob = offs + (size_t)b * HW * 128;
    float oy = b2f(ob[(size_t)pp * 128 + ch]);
    float ox = b2f(ob[(size_t)(pp + 1) * 128 + ch]);
    int gy = p >> 7, gx = p & 127;
    float cy = fminf(fmaxf(oy + (float)gy, 0.f), 127.f);
    float cx = fminf(fmaxf(ox + (float)gx, 0.f), 127.f);
    float y0f = floorf(cy), x0f = floorf(cx);
    int y0 = (int)y0f, x0i = (int)x0f;
    int y1 = (int)ceilf(cy), x1 = (int)ceilf(cx);
    const unsigned short* pl = xh + (size_t)b * HW * 64 + ci;
    float v_lt = b2f(pl[(size_t)(y0 * 128 + x0i) * 64]);
    float v_rb = b2f(pl[(size_t)(y1 * 128 + x1) * 64]);
    float v_lb = b2f(pl[(size_t)(y0 * 128 + x1) * 64]);
    float v_rt = b2f(pl[(size_t)(y1 * 128 + x0i) * 64]);
    float dy = cy - y0f, dx = cx - x0f;
    float v_t = fmaf(dy, v_rt - v_lt, v_lt);
    float v_b = fmaf(dy, v_rb - v_lb, v_lb);
    xdef[(size_t)bp * 64 + ci] = f2b(fmaf(dx, v_b - v_t, v_t));
}

extern "C" void kernel_launch(void* const* d_in, const int* in_sizes, int n_in,
                              void* d_out, int out_size, void* d_ws, size_t ws_size,
                              hipStream_t stream) {
    const float* x      = (const float*)d_in[0];
    const float* W_off  = (const float*)d_in[1];
    const float* W_conv = (const float*)d_in[2];
    const float* b_conv = (const float*)d_in[3];

    unsigned short* xh   = (unsigned short*)d_ws;            // 16.8 MB
    unsigned short* offs = xh + (size_t)DB * HW * 64;        // 33.6 MB
    unsigned short* xdef = offs + (size_t)DB * HW * 128;     // 16.8 MB
    unsigned short* wt1  = xdef + (size_t)DB * HW * 64;      // 147 KB
    unsigned short* wt2  = wt1 + 9 * 128 * 64;               // 74 KB
    float* out = (float*)d_out;

    xpose_kernel<<<dim3(HW / 64, DB), 256, 0, stream>>>(x, xh);
    wprep_kernel<<<(9 * 128 * 64 + 255) / 256, 256, 0, stream>>>(W_off, wt1, 128);
    wprep_kernel<<<(9 * 64 * 64 + 255) / 256, 256, 0, stream>>>(W_conv, wt2, 64);

    // conv1: COUT=128, 4 waves x 2 m-tiles, bf16 HWC offsets out
    conv_mfma_kernel<128, 2, true><<<dim3(256, DB), 256, 0, stream>>>(
        xh, wt1, nullptr, offs);

    deform_kernel<<<(DB * HW * 64) / 256, 256, 0, stream>>>(xh, offs, xdef);

    // conv2: COUT=64, 4 waves x 1 m-tile, fp32 NCHW out + bias
    conv_mfma_kernel<64, 1, false><<<dim3(256, DB), 256, 0, stream>>>(
        xdef, wt2, b_conv, out);
}

// Round 6
// 162.159 us; speedup vs baseline: 6.0749x; 1.2005x over previous
//
#include <hip/hip_runtime.h>

#define DH 128
#define DW 128
#define DB 8
#define DC 64
constexpr int HW = DH * DW;

typedef __attribute__((ext_vector_type(4))) float f32x4;
typedef __attribute__((ext_vector_type(16))) float f32x16;
typedef __attribute__((ext_vector_type(8))) short bf16x8;
typedef __attribute__((ext_vector_type(4))) unsigned int u32x4;

__device__ __forceinline__ unsigned short f2b(float f) {
    unsigned int u = __builtin_bit_cast(unsigned int, f);
    u = (u + 0x7FFFu + ((u >> 16) & 1u)) >> 16;   // RNE
    return (unsigned short)u;
}
__device__ __forceinline__ float b2f(unsigned short h) {
    unsigned int u = ((unsigned int)h) << 16;
    return __builtin_bit_cast(float, u);
}

// ---------- NCHW fp32 -> HWC bf16 transpose: xh[b][p][ci] ----------
__global__ __launch_bounds__(256) void xpose_kernel(
    const float* __restrict__ x, unsigned short* __restrict__ xh)
{
    __shared__ unsigned short sm[64 * 80];   // [pix][ci], pad 80
    const int b = blockIdx.y;
    const int p0 = blockIdx.x * 64;
    const int t = threadIdx.x;
    const int ci = t >> 2, q = t & 3;
    const float* xr = x + ((size_t)b * 64 + ci) * HW + p0;
#pragma unroll
    for (int j = 0; j < 4; ++j) {
        int pix = (j * 4 + q) * 4;
        float4 v = *(const float4*)(xr + pix);
        sm[(pix + 0) * 80 + ci] = f2b(v.x);
        sm[(pix + 1) * 80 + ci] = f2b(v.y);
        sm[(pix + 2) * 80 + ci] = f2b(v.z);
        sm[(pix + 3) * 80 + ci] = f2b(v.w);
    }
    __syncthreads();
    unsigned short* outp = xh + ((size_t)b * HW + p0) * 64;
    for (int i = t; i < 512; i += 256) {
        int pix = i >> 3, cq = i & 7;
        u32x4 v = *(const u32x4*)(sm + pix * 80 + cq * 8);
        *(u32x4*)(outp + pix * 64 + cq * 8) = v;
    }
}

// ---------- both weights OIHW fp32 -> [tap][co][ci] bf16 ----------
__global__ __launch_bounds__(256) void wprep_kernel(
    const float* __restrict__ wo, const float* __restrict__ wc,
    unsigned short* __restrict__ wt1, unsigned short* __restrict__ wt2)
{
    int id = blockIdx.x * 256 + threadIdx.x;
    const int N1 = 9 * 128 * 64, N2 = 9 * 64 * 64;
    if (id < N1) {
        int t = id / (128 * 64);
        int rem = id - t * 128 * 64;
        int co = rem >> 6, ci = rem & 63;
        wt1[id] = f2b(wo[(co * 64 + ci) * 9 + t]);
    } else if (id < N1 + N2) {
        int k = id - N1;
        int t = k / (64 * 64);
        int rem = k - t * 64 * 64;
        int co = rem >> 6, ci = rem & 63;
        wt2[k] = f2b(wc[(co * 64 + ci) * 9 + t]);
    }
}

// ---------- conv 3x3 implicit GEMM, 32x32x16 bf16 MFMA ----------
// 512 thr = 8 waves. Tile 16x16 pixels x COUT. Halo [18][18][64] bf16 in
// LDS (swz ^(hp&7)<<4), weights [co][ci] per tap double-buffered in LDS
// (swz ^(co&7)<<4, staged via inverse-swizzled global src + linear write).
// Wave (wm,wn): co-range wm*MI*32..+MI*32, pixel rows wn*4..+4.
// Per k-step (K=16): MI A-reads + 2 B-reads + 2*MI MFMA.
template<int COUT, int MI, bool HWC_BF16_OUT>
__global__ __launch_bounds__(512, 4) void conv_mfma_kernel(
    const unsigned short* __restrict__ xh,   // bf16 HWC [b][p][64]
    const unsigned short* __restrict__ wt,   // bf16 [9][COUT][64]
    const float* __restrict__ bias,
    void* __restrict__ outp)
{
    constexpr int WBYTES = COUT * 64 * 2;      // 16384 or 8192
    constexpr int SPASS = WBYTES / 8192;       // 16B per thread per pass
    __shared__ char sm[41472 + 2 * WBYTES];
    char* const wbuf0 = sm + 41472;
    char* const wbuf1 = sm + 41472 + WBYTES;

    const int tid = threadIdx.x;
    const int b = blockIdx.y;
    const int ty0 = (blockIdx.x >> 3) << 4;
    const int tx0 = (blockIdx.x & 7) << 4;
    const unsigned short* xb = xh + (size_t)b * HW * 64;

    // ---- prologue: issue weights tap0, stage halo, write weights ----
    u32x4 wreg[SPASS];
    {
        const char* wsrc = (const char*)wt;
#pragma unroll
        for (int s = 0; s < SPASS; ++s) {
            int L = (s * 512 + tid) * 16;
            wreg[s] = *(const u32x4*)(wsrc + (L ^ (((L >> 7) & 7) << 4)));
        }
    }
    for (int i = tid; i < 2592; i += 512) {     // 324 hp x 8 chunks
        int hp = i >> 3, cq = i & 7;
        int hy = hp / 18, hx = hp - hy * 18;
        int gy = ty0 + hy - 1, gx = tx0 + hx - 1;
        u32x4 v = {0u, 0u, 0u, 0u};
        if ((unsigned)gy < 128u && (unsigned)gx < 128u)
            v = *(const u32x4*)(xb + (size_t)((gy << 7) + gx) * 64 + cq * 8);
        *(u32x4*)(sm + ((hp * 128 + cq * 16) ^ ((hp & 7) << 4))) = v;
    }
#pragma unroll
    for (int s = 0; s < SPASS; ++s) {
        int L = (s * 512 + tid) * 16;
        *(u32x4*)(wbuf0 + L) = wreg[s];
    }
    __syncthreads();

    // ---- wave geometry ----
    const int lane = tid & 63;
    const int wv = tid >> 6;
    const int wm = wv & 1;
    const int wn = wv >> 1;
    const int n = lane & 31;
    const int half = lane >> 5;
    const int px = n & 15;
    const int pyb = wn * 4 + (n >> 4);          // +ni*2
    const int swzA = (lane & 7) << 4;
    const int rowA = (wm * (MI * 32) + n) * 128 + half * 16;

    int hp0[2];
#pragma unroll
    for (int ni = 0; ni < 2; ++ni)
        hp0[ni] = (pyb + ni * 2) * 18 + px;

    f32x16 acc[MI][2];
#pragma unroll
    for (int mi = 0; mi < MI; ++mi)
#pragma unroll
        for (int ni = 0; ni < 2; ++ni)
#pragma unroll
            for (int e = 0; e < 16; ++e) acc[mi][ni][e] = 0.f;

#pragma unroll
    for (int t9 = 0; t9 < 9; ++t9) {
        const int toff = (t9 / 3) * 18 + (t9 % 3);
        const char* wb = (t9 & 1) ? wbuf1 : wbuf0;
        u32x4 wr[SPASS];
        if (t9 < 8) {      // issue next tap's loads early (hide under MFMA)
            const char* wsrc = (const char*)(wt + (size_t)(t9 + 1) * COUT * 64);
#pragma unroll
            for (int s = 0; s < SPASS; ++s) {
                int L = (s * 512 + tid) * 16;
                wr[s] = *(const u32x4*)(wsrc + (L ^ (((L >> 7) & 7) << 4)));
            }
        }
#pragma unroll
        for (int kk = 0; kk < 4; ++kk) {
            const int kcol = kk * 32;
            bf16x8 a[MI], bv[2];
#pragma unroll
            for (int mi = 0; mi < MI; ++mi)
                a[mi] = *(const bf16x8*)(wb + ((rowA + mi * 4096 + kcol) ^ swzA));
#pragma unroll
            for (int ni = 0; ni < 2; ++ni) {
                int hp = hp0[ni] + toff;
                bv[ni] = *(const bf16x8*)(sm + ((hp * 128 + kcol + half * 16) ^ ((hp & 7) << 4)));
            }
#pragma unroll
            for (int mi = 0; mi < MI; ++mi)
#pragma unroll
                for (int ni = 0; ni < 2; ++ni)
                    acc[mi][ni] = __builtin_amdgcn_mfma_f32_32x32x16_bf16(
                        a[mi], bv[ni], acc[mi][ni], 0, 0, 0);
        }
        if (t9 < 8) {       // write-late after compute
            char* wbn = ((t9 + 1) & 1) ? wbuf1 : wbuf0;
#pragma unroll
            for (int s = 0; s < SPASS; ++s) {
                int L = (s * 512 + tid) * 16;
                *(u32x4*)(wbn + L) = wr[s];
            }
        }
        __syncthreads();
    }

    // ---- epilogue: D col=lane&31 (pixel), row=(r&3)+8*(r>>2)+4*half (co) ----
#pragma unroll
    for (int ni = 0; ni < 2; ++ni) {
        int py = pyb + ni * 2;
        int gp = (ty0 + py) * 128 + tx0 + px;
        if (HWC_BF16_OUT) {
            unsigned short* o = (unsigned short*)outp + ((size_t)b * HW + gp) * COUT;
#pragma unroll
            for (int mi = 0; mi < MI; ++mi) {
                int cob = wm * (MI * 32) + mi * 32 + half * 4;
#pragma unroll
                for (int g = 0; g < 4; ++g) {
                    uint2 pk;
                    pk.x = (unsigned)f2b(acc[mi][ni][g * 4 + 0]) |
                           ((unsigned)f2b(acc[mi][ni][g * 4 + 1]) << 16);
                    pk.y = (unsigned)f2b(acc[mi][ni][g * 4 + 2]) |
                           ((unsigned)f2b(acc[mi][ni][g * 4 + 3]) << 16);
                    *(uint2*)(o + cob + g * 8) = pk;
                }
            }
        } else {
            float* o = (float*)outp + (size_t)b * COUT * HW + gp;
#pragma unroll
            for (int mi = 0; mi < MI; ++mi) {
                int cob = wm * (MI * 32) + mi * 32 + half * 4;
#pragma unroll
                for (int g = 0; g < 4; ++g)
#pragma unroll
                    for (int r = 0; r < 4; ++r) {
                        int co = cob + g * 8 + r;
                        o[(size_t)co * HW] = acc[mi][ni][g * 4 + r] + bias[co];
                    }
            }
        }
    }
}

// ---------- deformable bilinear gather (HWC in/out) ----------
__global__ __launch_bounds__(256) void deform_kernel(
    const unsigned short* __restrict__ xh,     // bf16 HWC [b][p][64]
    const unsigned short* __restrict__ offs,   // bf16 HWC [b][p][128]
    unsigned short* __restrict__ xdef)         // bf16 HWC [b][p][64]
{
    int idx = blockIdx.x * 256 + threadIdx.x;  // (b, p, ci), ci fastest
    int ci = idx & 63;
    int bp = idx >> 6;
    int p = bp & (HW - 1);
    int b = bp >> 14;
    int ch = 2 * ci + (p >> 13);
    int pp = (2 * p) & (HW - 1);
    const unsigned short* ob = offs + (size_t)b * HW * 128;
    float oy = b2f(ob[(size_t)pp * 128 + ch]);
    float ox = b2f(ob[(size_t)(pp + 1) * 128 + ch]);
    int gy = p >> 7, gx = p & 127;
    float cy = fminf(fmaxf(oy + (float)gy, 0.f), 127.f);
    float cx = fminf(fmaxf(ox + (float)gx, 0.f), 127.f);
    float y0f = floorf(cy), x0f = floorf(cx);
    int y0 = (int)y0f, x0i = (int)x0f;
    int y1 = (int)ceilf(cy), x1 = (int)ceilf(cx);
    const unsigned short* pl = xh + (size_t)b * HW * 64 + ci;
    float v_lt = b2f(pl[(size_t)(y0 * 128 + x0i) * 64]);
    float v_rb = b2f(pl[(size_t)(y1 * 128 + x1) * 64]);
    float v_lb = b2f(pl[(size_t)(y0 * 128 + x1) * 64]);
    float v_rt = b2f(pl[(size_t)(y1 * 128 + x0i) * 64]);
    float dy = cy - y0f, dx = cx - x0f;
    float v_t = fmaf(dy, v_rt - v_lt, v_lt);
    float v_b = fmaf(dy, v_rb - v_lb, v_lb);
    xdef[(size_t)bp * 64 + ci] = f2b(fmaf(dx, v_b - v_t, v_t));
}

extern "C" void kernel_launch(void* const* d_in, const int* in_sizes, int n_in,
                              void* d_out, int out_size, void* d_ws, size_t ws_size,
                              hipStream_t stream) {
    const float* x      = (const float*)d_in[0];
    const float* W_off  = (const float*)d_in[1];
    const float* W_conv = (const float*)d_in[2];
    const float* b_conv = (const float*)d_in[3];

    unsigned short* xh   = (unsigned short*)d_ws;            // 16.8 MB
    unsigned short* offs = xh + (size_t)DB * HW * 64;        // 33.6 MB
    unsigned short* xdef = offs + (size_t)DB * HW * 128;     // 16.8 MB
    unsigned short* wt1  = xdef + (size_t)DB * HW * 64;      // 147 KB
    unsigned short* wt2  = wt1 + 9 * 128 * 64;               // 74 KB
    float* out = (float*)d_out;

    xpose_kernel<<<dim3(HW / 64, DB), 256, 0, stream>>>(x, xh);
    wprep_kernel<<<(9 * 128 * 64 + 9 * 64 * 64 + 255) / 256, 256, 0, stream>>>(
        W_off, W_conv, wt1, wt2);

    // conv1: COUT=128, MI=2, bf16 HWC offsets out
    conv_mfma_kernel<128, 2, true><<<dim3(64, DB), 512, 0, stream>>>(
        xh, wt1, nullptr, offs);

    deform_kernel<<<(DB * HW * 64) / 256, 256, 0, stream>>>(xh, offs, xdef);

    // conv2: COUT=64, MI=1, fp32 NCHW out + bias
    conv_mfma_kernel<64, 1, false><<<dim3(64, DB), 512, 0, stream>>>(
        xdef, wt2, b_conv, out);
}